// Round 7
// baseline (314.514 us; speedup 1.0000x reference)
//
#include <hip/hip_runtime.h>

// Problem constants: B=8, C=512, Cq=64, W=2048.
#define B_  8
#define C_  512
#define CQ_ 64
#define W_  2048
#define NROW 640   // stacked output rows: 64 q + 64 k + 512 v

typedef __attribute__((ext_vector_type(8))) short  short8;   // 8 bf16 (MFMA A/B frag)
typedef __attribute__((ext_vector_type(4))) float  f32x4;    // MFMA C/D frag
typedef unsigned short ushort;
typedef unsigned long long ull;

// Workspace layout (float slots). Total = 15,007,744 floats = 60.0 MB.
static constexpr size_t OFF_VB  = 0;                                    // V bf16 [B][C][W]
static constexpr size_t OFF_QTH = OFF_VB  + (size_t)B_ * C_ * W_ / 2;   // qT hi bf16 [B][W][64]
static constexpr size_t OFF_QTL = OFF_QTH + (size_t)B_ * W_ * CQ_ / 2;
static constexpr size_t OFF_KTH = OFF_QTL + (size_t)B_ * W_ * CQ_ / 2;
static constexpr size_t OFF_KTL = OFF_KTH + (size_t)B_ * W_ * CQ_ / 2;
static constexpr size_t OFF_XTH = OFF_KTL + (size_t)B_ * W_ * CQ_ / 2;  // xT hi bf16 [B][W][C]
static constexpr size_t OFF_XTL = OFF_XTH + (size_t)B_ * W_ * C_ / 2;
static constexpr size_t OFF_WH  = OFF_XTL + (size_t)B_ * W_ * C_ / 2;   // Wall hi bf16 [640][C]
static constexpr size_t OFF_WL  = OFF_WH  + (size_t)NROW * C_ / 2;      // Wall lo

static __device__ __forceinline__ ushort f2bf(float f) {
    unsigned int u = __builtin_bit_cast(unsigned int, f);
    u += 0x7fffu + ((u >> 16) & 1u);          // round-to-nearest-even
    return (ushort)(u >> 16);
}
static __device__ __forceinline__ float bf2f(ushort h) {
    unsigned int u = ((unsigned int)h) << 16;
    return __builtin_bit_cast(float, u);
}
static __device__ __forceinline__ ull pack4(const ushort* p) {
    return (ull)p[0] | ((ull)p[1] << 16) | ((ull)p[2] << 32) | ((ull)p[3] << 48);
}

// ---------------------------------------------------------------------------
// Kernel 0a: pack Wq/Wk/Wv into stacked [640][512] hi/lo split-bf16.
// ---------------------------------------------------------------------------
__global__ __launch_bounds__(256) void k_wsplit(
    const float* __restrict__ Wq, const float* __restrict__ Wk,
    const float* __restrict__ Wv, ushort* __restrict__ wh, ushort* __restrict__ wl)
{
    const int idx = (blockIdx.x * 256 + threadIdx.x) * 4;   // < 640*512
    const int row = idx >> 9, col = idx & 511;
    const float* src;
    if (row < 64)       src = Wq + (size_t)row * C_ + col;
    else if (row < 128) src = Wk + (size_t)(row - 64) * C_ + col;
    else                src = Wv + (size_t)(row - 128) * C_ + col;
    float4 v = *reinterpret_cast<const float4*>(src);
    float vv[4] = {v.x, v.y, v.z, v.w};
    ushort h[4], lo[4];
    #pragma unroll
    for (int j = 0; j < 4; ++j) {
        h[j]  = f2bf(vv[j]);
        lo[j] = f2bf(vv[j] - bf2f(h[j]));
    }
    *reinterpret_cast<ull*>(wh + idx) = pack4(h);
    *reinterpret_cast<ull*>(wl + idx) = pack4(lo);
}

// ---------------------------------------------------------------------------
// Kernel 0b: transpose x [B][C][W] fp32 -> xT hi/lo bf16 [B][W][C].
// ---------------------------------------------------------------------------
__global__ __launch_bounds__(256) void k_xt(
    const float* __restrict__ x, ushort* __restrict__ xth, ushort* __restrict__ xtl)
{
    const int b = blockIdx.z, c0 = blockIdx.y * 64, w0 = blockIdx.x * 64;
    __shared__ float ts[64][65];
    const int t = threadIdx.x;
    #pragma unroll
    for (int m = 0; m < 4; ++m) {
        int fi = m * 256 + t;
        int c = fi >> 4, c4 = fi & 15;
        float4 v = *reinterpret_cast<const float4*>(x + ((size_t)b * C_ + c0 + c) * W_ + w0 + c4 * 4);
        ts[c][c4 * 4 + 0] = v.x; ts[c][c4 * 4 + 1] = v.y;
        ts[c][c4 * 4 + 2] = v.z; ts[c][c4 * 4 + 3] = v.w;
    }
    __syncthreads();
    #pragma unroll
    for (int m = 0; m < 4; ++m) {
        int w  = m * 16 + (t >> 4);
        int cc = (t & 15) * 4;
        ushort h[4], lo[4];
        #pragma unroll
        for (int j = 0; j < 4; ++j) {
            float v = ts[cc + j][w];
            h[j]  = f2bf(v);
            lo[j] = f2bf(v - bf2f(h[j]));
        }
        size_t base = ((size_t)b * W_ + w0 + w) * C_ + c0 + cc;
        *reinterpret_cast<ull*>(xth + base) = pack4(h);
        *reinterpret_cast<ull*>(xtl + base) = pack4(lo);
    }
}

// ---------------------------------------------------------------------------
// Kernel 1 (PROVEN structure, new Q/K epilogue): projection GEMM via MFMA.
// Out[r][w] = sum_c Wall[r][c]*x[c][w]. Q/K (rows 0..127): split-bf16 3-MFMA,
// now written TRANSPOSED as qT/kT hi/lo bf16 [B][W][64] (8B-packed stores).
// V rows: hh only, bf16 [B][C][W]. grid: (32, B), 512 thr = 8 waves.
// ---------------------------------------------------------------------------
__global__ __launch_bounds__(512) void k_projm(
    const ushort* __restrict__ wh, const ushort* __restrict__ wl,
    const ushort* __restrict__ xth, const ushort* __restrict__ xtl,
    const float* __restrict__ bq, const float* __restrict__ bk,
    const float* __restrict__ bv,
    ushort* __restrict__ qth, ushort* __restrict__ qtl,
    ushort* __restrict__ kth, ushort* __restrict__ ktl,
    ushort* __restrict__ vb)
{
    const int b = blockIdx.y, w0 = blockIdx.x * 64;
    const int t = threadIdx.x, l = t & 63, wid = t >> 6;
    const int lr = l & 15, lkb = (l >> 4) * 8;

    f32x4 acc[5][4];
    #pragma unroll
    for (int m = 0; m < 5; ++m)
        #pragma unroll
        for (int n = 0; n < 4; ++n) acc[m][n] = (f32x4){0.f, 0.f, 0.f, 0.f};

    const size_t xbase = ((size_t)b * W_ + w0 + lr) * C_ + lkb;

    for (int kc = 0; kc < 16; ++kc) {
        short8 bhf[4], blf[4];
        #pragma unroll
        for (int n = 0; n < 4; ++n) {
            bhf[n] = *reinterpret_cast<const short8*>(xth + xbase + (size_t)n * 16 * C_ + kc * 32);
            blf[n] = *reinterpret_cast<const short8*>(xtl + xbase + (size_t)n * 16 * C_ + kc * 32);
        }
        #pragma unroll
        for (int m = 0; m < 5; ++m) {
            const int arow = (wid + m * 8) * 16 + lr;
            const size_t abase = (size_t)arow * C_ + kc * 32 + lkb;
            short8 ah = *reinterpret_cast<const short8*>(wh + abase);
            #pragma unroll
            for (int n = 0; n < 4; ++n)
                acc[m][n] = __builtin_amdgcn_mfma_f32_16x16x32_bf16(ah, bhf[n], acc[m][n], 0, 0, 0);
            if (m == 0) {   // Q/K group: add lo-plane cross terms
                short8 al = *reinterpret_cast<const short8*>(wl + abase);
                #pragma unroll
                for (int n = 0; n < 4; ++n) {
                    acc[m][n] = __builtin_amdgcn_mfma_f32_16x16x32_bf16(al, bhf[n], acc[m][n], 0, 0, 0);
                    acc[m][n] = __builtin_amdgcn_mfma_f32_16x16x32_bf16(ah, blf[n], acc[m][n], 0, 0, 0);
                }
            }
        }
    }

    // Epilogue. D layout (m89-validated): col = l&15, row = (l>>4)*4 + reg.
    #pragma unroll
    for (int m = 0; m < 5; ++m) {
        const int rbase16 = (wid + m * 8) * 16;
        if (rbase16 < 128) {
            // Q (rows 0-63) / K (rows 64-127): split hi/lo, write transposed [w][row].
            ushort* oh = (rbase16 < 64) ? qth : kth;
            ushort* ol = (rbase16 < 64) ? qtl : ktl;
            const float* bias = (rbase16 < 64) ? bq : bk;
            const int rb = rbase16 & 63;
            #pragma unroll
            for (int n = 0; n < 4; ++n) {
                const int wcol = w0 + n * 16 + lr;
                ushort h4[4], l4[4];
                #pragma unroll
                for (int r = 0; r < 4; ++r) {
                    const int rowl = rb + (l >> 4) * 4 + r;
                    float val = acc[m][n][r] + bias[rowl];
                    h4[r] = f2bf(val);
                    l4[r] = f2bf(val - bf2f(h4[r]));
                }
                size_t base = ((size_t)b * W_ + wcol) * CQ_ + rb + (l >> 4) * 4;
                *reinterpret_cast<ull*>(oh + base) = pack4(h4);
                *reinterpret_cast<ull*>(ol + base) = pack4(l4);
            }
        } else {
            // V rows: bf16 [B][C][W].
            #pragma unroll
            for (int n = 0; n < 4; ++n) {
                const int wcol = w0 + n * 16 + lr;
                #pragma unroll
                for (int r = 0; r < 4; ++r) {
                    const int rl = rbase16 - 128 + (l >> 4) * 4 + r;
                    vb[((size_t)b * C_ + rl) * W_ + wcol] = f2bf(acc[m][n][r] + bv[rl]);
                }
            }
        }
    }
}

// ---------------------------------------------------------------------------
// Kernel 2 (NEW): fused flash attention. Per block: 64 i-cols x all 512 c.
// grid: (W/64=32, B), 512 thr = 8 waves.
//   waves 0-3: QK^T (split-bf16 qT/kT register frags) for 16 i-rows each,
//              online softmax (running m,l), P bf16 -> swizzled LDS + scales.
//   all waves: rescale acc (64c x 64i), PV MFMA (V register frags from L2,
//              P frags from LDS via proven XOR-swizzle read).
// Epilogue: out = gamma * acc / l + x.
// ---------------------------------------------------------------------------
__global__ __launch_bounds__(512) void k_flash(
    const ushort* __restrict__ qth, const ushort* __restrict__ qtl,
    const ushort* __restrict__ kth, const ushort* __restrict__ ktl,
    const ushort* __restrict__ vb,
    const float* __restrict__ x, const float* __restrict__ gamma,
    float* __restrict__ out)
{
    const int b  = blockIdx.y;
    const int i0 = blockIdx.x * 64;
    const int t = threadIdx.x, l = t & 63, wid = t >> 6;
    const int lr = l & 15, lkb = (l >> 4) * 8;
    const int ib = (wid & 3) * 16;   // QK i-slice base (waves 0-3 only)

    __shared__ __align__(16) ushort Ps[64 * 64];  // P bf16 [i][j], XOR-swizzled
    __shared__ float scale_lds[64];
    __shared__ float l_lds[64];

    // Q fragments (rows i0+ib+lr), hi/lo, kc chunks. Only waves 0-3 use them.
    short8 qh[2], ql[2];
    if (wid < 4) {
        const size_t qbase = ((size_t)b * W_ + i0 + ib + lr) * CQ_ + lkb;
        #pragma unroll
        for (int kc = 0; kc < 2; ++kc) {
            qh[kc] = *reinterpret_cast<const short8*>(qth + qbase + kc * 32);
            ql[kc] = *reinterpret_cast<const short8*>(qtl + qbase + kc * 32);
        }
    }

    f32x4 acc[4][4];
    #pragma unroll
    for (int i = 0; i < 4; ++i)
        #pragma unroll
        for (int j = 0; j < 4; ++j) acc[i][j] = (f32x4){0.f, 0.f, 0.f, 0.f};

    float mrun[4] = {-3.0e38f, -3.0e38f, -3.0e38f, -3.0e38f};
    float lrun[4] = {0.f, 0.f, 0.f, 0.f};

    const ushort* vbase = vb + ((size_t)b * C_ + wid * 64) * W_;

    for (int jt = 0; jt < 32; ++jt) {
        const int j0 = jt * 64;

        if (wid < 4) {
            // --- QK^T: e[fn] = E[i-slice 16][j 64] ---
            f32x4 e[4];
            #pragma unroll
            for (int n = 0; n < 4; ++n) e[n] = (f32x4){0.f, 0.f, 0.f, 0.f};
            #pragma unroll
            for (int kc = 0; kc < 2; ++kc) {
                short8 bh[4], bl[4];
                #pragma unroll
                for (int n = 0; n < 4; ++n) {
                    const size_t ka = ((size_t)b * W_ + j0 + n * 16 + lr) * CQ_ + kc * 32 + lkb;
                    bh[n] = *reinterpret_cast<const short8*>(kth + ka);
                    bl[n] = *reinterpret_cast<const short8*>(ktl + ka);
                }
                #pragma unroll
                for (int n = 0; n < 4; ++n) {
                    e[n] = __builtin_amdgcn_mfma_f32_16x16x32_bf16(qh[kc], bh[n], e[n], 0, 0, 0);
                    e[n] = __builtin_amdgcn_mfma_f32_16x16x32_bf16(ql[kc], bh[n], e[n], 0, 0, 0);
                    e[n] = __builtin_amdgcn_mfma_f32_16x16x32_bf16(qh[kc], bl[n], e[n], 0, 0, 0);
                }
            }
            // --- online softmax update (rows ib + (l>>4)*4 + r) ---
            float rmax[4];
            #pragma unroll
            for (int r = 0; r < 4; ++r)
                rmax[r] = fmaxf(fmaxf(e[0][r], e[1][r]), fmaxf(e[2][r], e[3][r]));
            #pragma unroll
            for (int off = 1; off <= 8; off <<= 1)
                #pragma unroll
                for (int r = 0; r < 4; ++r)
                    rmax[r] = fmaxf(rmax[r], __shfl_xor(rmax[r], off));
            float sc[4];
            #pragma unroll
            for (int r = 0; r < 4; ++r) {
                const float mnew = fmaxf(mrun[r], rmax[r]);
                sc[r] = __expf(mrun[r] - mnew);
                mrun[r] = mnew;
            }
            float rsum[4] = {0.f, 0.f, 0.f, 0.f};
            #pragma unroll
            for (int n = 0; n < 4; ++n)
                #pragma unroll
                for (int r = 0; r < 4; ++r) {
                    const float p = __expf(e[n][r] - mrun[r]);
                    e[n][r] = p;
                    rsum[r] += p;
                }
            #pragma unroll
            for (int off = 1; off <= 8; off <<= 1)
                #pragma unroll
                for (int r = 0; r < 4; ++r)
                    rsum[r] += __shfl_xor(rsum[r], off);
            #pragma unroll
            for (int r = 0; r < 4; ++r)
                lrun[r] = lrun[r] * sc[r] + rsum[r];
            // --- write P (bf16, swizzled) + scales ---
            #pragma unroll
            for (int n = 0; n < 4; ++n)
                #pragma unroll
                for (int r = 0; r < 4; ++r) {
                    const int row = ib + (l >> 4) * 4 + r;
                    const int idx = (row * 64 + n * 16 + lr) ^ ((row & 7) << 3);
                    Ps[idx] = f2bf(e[n][r]);
                }
            if (lr == 0) {
                #pragma unroll
                for (int r = 0; r < 4; ++r)
                    scale_lds[ib + (l >> 4) * 4 + r] = sc[r];
            }
        }
        __syncthreads();

        // --- all waves: rescale acc, PV ---
        float s4[4];
        #pragma unroll
        for (int fi = 0; fi < 4; ++fi) s4[fi] = scale_lds[fi * 16 + lr];
        #pragma unroll
        for (int fc = 0; fc < 4; ++fc)
            #pragma unroll
            for (int fi = 0; fi < 4; ++fi)
                acc[fc][fi] *= s4[fi];
        #pragma unroll
        for (int kc = 0; kc < 2; ++kc) {
            short8 a[4], p[4];
            #pragma unroll
            for (int f = 0; f < 4; ++f) {
                a[f] = *reinterpret_cast<const short8*>(vbase + (size_t)(f * 16 + lr) * W_ + j0 + kc * 32 + lkb);
                const int row = f * 16 + lr;
                const int idx = ((row * 64) + kc * 32 + lkb) ^ ((row & 7) << 3);
                p[f] = *reinterpret_cast<const short8*>(&Ps[idx]);
            }
            #pragma unroll
            for (int fc = 0; fc < 4; ++fc)
                #pragma unroll
                for (int fi = 0; fi < 4; ++fi)
                    acc[fc][fi] = __builtin_amdgcn_mfma_f32_16x16x32_bf16(a[fc], p[fi], acc[fc][fi], 0, 0, 0);
        }
        __syncthreads();
    }

    // --- final: publish l, normalize, epilogue out = g*acc/l + x ---
    if (wid < 4 && lr == 0) {
        #pragma unroll
        for (int r = 0; r < 4; ++r)
            l_lds[ib + (l >> 4) * 4 + r] = lrun[r];
    }
    __syncthreads();
    float linv[4];
    #pragma unroll
    for (int fi = 0; fi < 4; ++fi) linv[fi] = 1.0f / l_lds[fi * 16 + lr];

    const float g = gamma[0];
    #pragma unroll
    for (int fc = 0; fc < 4; ++fc) {
        const int c = wid * 64 + fc * 16 + (l >> 4) * 4;
        #pragma unroll
        for (int fi = 0; fi < 4; ++fi) {
            const int icol = i0 + fi * 16 + lr;
            #pragma unroll
            for (int r = 0; r < 4; ++r) {
                const size_t addr = ((size_t)b * C_ + c + r) * W_ + icol;
                out[addr] = g * acc[fc][fi][r] * linv[fi] + x[addr];
            }
        }
    }
}

// ---------------------------------------------------------------------------
extern "C" void kernel_launch(void* const* d_in, const int* in_sizes, int n_in,
                              void* d_out, int out_size, void* d_ws, size_t ws_size,
                              hipStream_t stream)
{
    const float* x     = (const float*)d_in[0];
    const float* Wq    = (const float*)d_in[1];
    const float* bq    = (const float*)d_in[2];
    const float* Wk    = (const float*)d_in[3];
    const float* bk    = (const float*)d_in[4];
    const float* Wv    = (const float*)d_in[5];
    const float* bv    = (const float*)d_in[6];
    const float* gamma = (const float*)d_in[7];
    float* out = (float*)d_out;
    float* ws  = (float*)d_ws;

    ushort* vbf = (ushort*)(ws + OFF_VB);
    ushort* qth = (ushort*)(ws + OFF_QTH);
    ushort* qtl = (ushort*)(ws + OFF_QTL);
    ushort* kth = (ushort*)(ws + OFF_KTH);
    ushort* ktl = (ushort*)(ws + OFF_KTL);
    ushort* xth = (ushort*)(ws + OFF_XTH);
    ushort* xtl = (ushort*)(ws + OFF_XTL);
    ushort* wh  = (ushort*)(ws + OFF_WH);
    ushort* wl  = (ushort*)(ws + OFF_WL);

    hipLaunchKernelGGL(k_wsplit, dim3(NROW * C_ / 1024, 1, 1), dim3(256), 0, stream,
                       Wq, Wk, Wv, wh, wl);
    hipLaunchKernelGGL(k_xt,     dim3(W_ / 64, C_ / 64, B_), dim3(256), 0, stream,
                       x, xth, xtl);
    hipLaunchKernelGGL(k_projm,  dim3(W_ / 64, B_, 1), dim3(512), 0, stream,
                       wh, wl, xth, xtl, bq, bk, bv, qth, qtl, kth, ktl, vbf);
    hipLaunchKernelGGL(k_flash,  dim3(W_ / 64, B_, 1), dim3(512), 0, stream,
                       qth, qtl, kth, ktl, vbf, x, gamma, out);
}